// Round 5
// baseline (271.278 us; speedup 1.0000x reference)
//
#include <hip/hip_runtime.h>
#include <hip/hip_bf16.h>

typedef __attribute__((ext_vector_type(8))) short short8;
typedef __attribute__((ext_vector_type(4))) short short4v;
typedef __attribute__((ext_vector_type(4))) float f32x4;

__device__ __forceinline__ short f2bf(float f) {
    union { float f; unsigned u; } v; v.f = f;
    unsigned r = (v.u + 0x7fffu + ((v.u >> 16) & 1u)) >> 16;
    return (short)r;
}
__device__ __forceinline__ float bf2f(short s) {
    union { unsigned u; float f; } v; v.u = ((unsigned)(unsigned short)s) << 16;
    return v.f;
}
__device__ __forceinline__ f32x4 zero4() { f32x4 z = {0.f, 0.f, 0.f, 0.f}; return z; }

// async global->LDS, 16B/lane; LDS dest = wave-uniform base, lane i lands at base+i*16
__device__ __forceinline__ void gl16(const void* g, void* l) {
    __builtin_amdgcn_global_load_lds(
        (const __attribute__((address_space(1))) void*)g,
        (__attribute__((address_space(3))) void*)l, 16, 0, 0);
}

// ---------------------------------------------------------------------------
// convertA: fp32 -> bf16 copies (before proj).
//  z=0: qb=q [4096x1536] -> d_out   z=1: kb=k -> d_out+12MB
//  z=2: Wqb=Wq[:512] [512x1536]     z=3: Wkb=Wk[:512]
// ---------------------------------------------------------------------------
__global__ __launch_bounds__(256) void convertA_kernel(
    const float* __restrict__ q, const float* __restrict__ k,
    const float* __restrict__ Wq, const float* __restrict__ Wk,
    short* __restrict__ qb, short* __restrict__ kb,
    short* __restrict__ Wqb, short* __restrict__ Wkb)
{
    const int e0 = (blockIdx.x * 256 + threadIdx.x) * 8;
    const float* src; short* dst; int n;
    switch (blockIdx.z) {
    case 0:  n = 6291456; src = q + e0;  dst = qb;  break;
    case 1:  n = 6291456; src = k + e0;  dst = kb;  break;
    case 2:  n = 786432;  src = Wq + e0; dst = Wqb; break;
    default: n = 786432;  src = Wk + e0; dst = Wkb; break;
    }
    if (e0 >= n) return;
    float4 f0 = ((const float4*)src)[0];
    float4 f1 = ((const float4*)src)[1];
    short8 o;
    o[0]=f2bf(f0.x); o[1]=f2bf(f0.y); o[2]=f2bf(f0.z); o[3]=f2bf(f0.w);
    o[4]=f2bf(f1.x); o[5]=f2bf(f1.y); o[6]=f2bf(f1.z); o[7]=f2bf(f1.w);
    *(short8*)(dst + e0) = o;
}

// convertB (after flash): Wob = Wo[:, :512] -> bf16 [1536x512]
__global__ __launch_bounds__(256) void convertB_kernel(
    const float* __restrict__ Wo, short* __restrict__ Wob)
{
    const int e0 = (blockIdx.x * 256 + threadIdx.x) * 8;   // < 786432
    const float* src = Wo + (size_t)(e0 >> 9) * 1536 + (e0 & 511);
    float4 f0 = ((const float4*)src)[0];
    float4 f1 = ((const float4*)src)[1];
    short8 o;
    o[0]=f2bf(f0.x); o[1]=f2bf(f0.y); o[2]=f2bf(f0.z); o[3]=f2bf(f0.w);
    o[4]=f2bf(f1.x); o[5]=f2bf(f1.y); o[6]=f2bf(f1.z); o[7]=f2bf(f1.w);
    *(short8*)(Wob + e0) = o;
}

// ---------------------------------------------------------------------------
// bf16 GEMM, m97 structure: C[M,N] = A[M,K] @ B[N,K]^T, 128x128xBK32 tiles,
// 4 waves 2x2, global_load_lds(16B) staging into unpadded [128][32] LDS.
// STORE: 0 = bf16 row-major, 2 = fp32 row-major.
// ---------------------------------------------------------------------------
template<int STORE>
__device__ __forceinline__ void gemm97(
    const short* __restrict__ A, const short* __restrict__ B, void* __restrict__ Cp,
    int K, int lda, int ldb, int ldc, short* As, short* Bs)
{
    const int bm = blockIdx.y * 128;
    const int bn = blockIdx.x * 128;
    const int tid = threadIdx.x;
    const int w = tid >> 6;
    const int lane = tid & 63;
    const int l15 = lane & 15;
    const int quad = lane >> 4;
    const int wm = (w >> 1) * 64;
    const int wn = (w & 1) * 64;

    const int srow = w * 32 + (lane >> 2);
    const int scol = (lane & 3) * 8;
    const short* ga = A + (size_t)(bm + srow) * lda + scol;
    const short* gb = B + (size_t)(bn + srow) * ldb + scol;
    short* laA0 = &As[(w * 32) * 32];
    short* laA1 = &As[(w * 32 + 16) * 32];
    short* laB0 = &Bs[(w * 32) * 32];
    short* laB1 = &Bs[(w * 32 + 16) * 32];

    f32x4 acc[4][4];
#pragma unroll
    for (int i = 0; i < 4; i++)
#pragma unroll
        for (int j = 0; j < 4; j++) acc[i][j] = zero4();

    for (int k0 = 0; k0 < K; k0 += 32) {
        __syncthreads();
        gl16(ga + k0, laA0);
        gl16(ga + k0 + (size_t)16 * lda, laA1);
        gl16(gb + k0, laB0);
        gl16(gb + k0 + (size_t)16 * ldb, laB1);
        __syncthreads();

        short8 af[4], bf[4];
#pragma unroll
        for (int i = 0; i < 4; i++)
            af[i] = *(const short8*)&As[(wm + i * 16 + l15) * 32 + quad * 8];
#pragma unroll
        for (int j = 0; j < 4; j++)
            bf[j] = *(const short8*)&Bs[(wn + j * 16 + l15) * 32 + quad * 8];
#pragma unroll
        for (int i = 0; i < 4; i++)
#pragma unroll
            for (int j = 0; j < 4; j++)
                acc[i][j] = __builtin_amdgcn_mfma_f32_16x16x32_bf16(af[i], bf[j], acc[i][j], 0, 0, 0);
    }

#pragma unroll
    for (int i = 0; i < 4; i++)
#pragma unroll
        for (int j = 0; j < 4; j++) {
            const int col = bn + wn + j * 16 + l15;
            const int row0 = bm + wm + i * 16 + quad * 4;
#pragma unroll
            for (int r = 0; r < 4; r++) {
                if constexpr (STORE == 0)
                    ((short*)Cp)[(size_t)(row0 + r) * ldc + col] = f2bf(acc[i][j][r]);
                else
                    ((float*)Cp)[(size_t)(row0 + r) * ldc + col] = acc[i][j][r];
            }
        }
}

// ---------------------------------------------------------------------------
// fp32-input GEMM (proven core): C = A @ B^T, staged+converted via LDS.
// STORE 1 = bf16 transposed (C^T[n][m]).
// ---------------------------------------------------------------------------
__device__ __forceinline__ void gemm_f32_bt_T(
    const float* __restrict__ A, const float* __restrict__ Bw, short* __restrict__ Cp,
    int K, int lda, int ldb, int ldc, short* As, short* Bs)
{
    const int bm = blockIdx.y * 128;
    const int bn = blockIdx.x * 128;
    const int tid = threadIdx.x;
    const int w = tid >> 6;
    const int lane = tid & 63;
    const int l15 = lane & 15;
    const int quad = lane >> 4;
    const int wm = (w >> 1) * 64;
    const int wn = (w & 1) * 64;
    const int srow = tid >> 1;
    const int scol = (tid & 1) * 16;

    f32x4 acc[4][4];
#pragma unroll
    for (int i = 0; i < 4; i++)
#pragma unroll
        for (int j = 0; j < 4; j++) acc[i][j] = zero4();

    for (int k0 = 0; k0 < K; k0 += 32) {
        __syncthreads();
        {
            const float* src = A + (size_t)(bm + srow) * lda + k0 + scol;
            short* dst = &As[srow * 40 + scol];
            const float4* s4 = (const float4*)src;
            float4 f0 = s4[0], f1 = s4[1], f2 = s4[2], f3 = s4[3];
            short8 t0, t1;
            t0[0]=f2bf(f0.x); t0[1]=f2bf(f0.y); t0[2]=f2bf(f0.z); t0[3]=f2bf(f0.w);
            t0[4]=f2bf(f1.x); t0[5]=f2bf(f1.y); t0[6]=f2bf(f1.z); t0[7]=f2bf(f1.w);
            t1[0]=f2bf(f2.x); t1[1]=f2bf(f2.y); t1[2]=f2bf(f2.z); t1[3]=f2bf(f2.w);
            t1[4]=f2bf(f3.x); t1[5]=f2bf(f3.y); t1[6]=f2bf(f3.z); t1[7]=f2bf(f3.w);
            *(short8*)dst = t0; *(short8*)(dst + 8) = t1;
        }
        {
            const float* src = Bw + (size_t)(bn + srow) * ldb + k0 + scol;
            short* dst = &Bs[srow * 40 + scol];
            const float4* s4 = (const float4*)src;
            float4 f0 = s4[0], f1 = s4[1], f2 = s4[2], f3 = s4[3];
            short8 t0, t1;
            t0[0]=f2bf(f0.x); t0[1]=f2bf(f0.y); t0[2]=f2bf(f0.z); t0[3]=f2bf(f0.w);
            t0[4]=f2bf(f1.x); t0[5]=f2bf(f1.y); t0[6]=f2bf(f1.z); t0[7]=f2bf(f1.w);
            t1[0]=f2bf(f2.x); t1[1]=f2bf(f2.y); t1[2]=f2bf(f2.z); t1[3]=f2bf(f2.w);
            t1[4]=f2bf(f3.x); t1[5]=f2bf(f3.y); t1[6]=f2bf(f3.z); t1[7]=f2bf(f3.w);
            *(short8*)dst = t0; *(short8*)(dst + 8) = t1;
        }
        __syncthreads();

        short8 af[4], bfr[4];
#pragma unroll
        for (int i = 0; i < 4; i++)
            af[i] = *(const short8*)&As[(wm + i * 16 + l15) * 40 + quad * 8];
#pragma unroll
        for (int j = 0; j < 4; j++)
            bfr[j] = *(const short8*)&Bs[(wn + j * 16 + l15) * 40 + quad * 8];
#pragma unroll
        for (int i = 0; i < 4; i++)
#pragma unroll
            for (int j = 0; j < 4; j++)
                acc[i][j] = __builtin_amdgcn_mfma_f32_16x16x32_bf16(af[i], bfr[j], acc[i][j], 0, 0, 0);
    }

#pragma unroll
    for (int i = 0; i < 4; i++)
#pragma unroll
        for (int j = 0; j < 4; j++) {
            const int col = bn + wn + j * 16 + l15;
            const int row0 = bm + wm + i * 16 + quad * 4;
            short4v p;
#pragma unroll
            for (int r = 0; r < 4; r++) p[r] = f2bf(acc[i][j][r]);
            *(short4v*)&Cp[(size_t)col * ldc + row0] = p;
        }
}

// z=0: qh = qb@Wqb^T; z=1: kh = kb@Wkb^T; z=2: vT = (v[:,512:1024]@Wv^T)^T
__global__ __launch_bounds__(256) void proj_kernel(
    const short* __restrict__ qb, const short* __restrict__ kb, const float* __restrict__ v,
    const short* __restrict__ Wqb, const short* __restrict__ Wkb, const float* __restrict__ Wv,
    short* __restrict__ qh, short* __restrict__ kh, short* __restrict__ vT)
{
    __shared__ short smem[2][5120];
    switch (blockIdx.z) {
    case 0:  gemm97<0>(qb, Wqb, qh, 1536, 1536, 1536, 512, smem[0], smem[1]); break;
    case 1:  gemm97<0>(kb, Wkb, kh, 1536, 1536, 1536, 512, smem[0], smem[1]); break;
    default: gemm_f32_bt_T(v + 512, Wv, vT, 512, 1536, 512, 4096, smem[0], smem[1]); break;
    }
}

// out[4096,1536] = attn[4096,512] @ Wob[1536,512]^T (fp32 out)
__global__ __launch_bounds__(256) void outproj_kernel(
    const short* __restrict__ attn, const short* __restrict__ Wob, float* __restrict__ out)
{
    __shared__ short smem[2][4096];
    gemm97<2>(attn, Wob, out, 512, 512, 512, 1536, smem[0], smem[1]);
}

// Interleaved-pair RoPE in place on bf16 [4096,512] (proven version).
__global__ __launch_bounds__(256) void rope_kernel(short* __restrict__ qh, short* __restrict__ kh)
{
    short* buf = blockIdx.z ? kh : qh;
    const int e0 = (blockIdx.x * 256 + threadIdx.x) * 8;
    const int row = e0 >> 9;
    const int c0 = e0 & 511;
    const float pos = (float)(row & 2047);
    short8 xv = *(short8*)&buf[e0];
    short8 ov;
#pragma unroll
    for (int p = 0; p < 4; p++) {
        const int pair = ((c0 + 2 * p) & 127) >> 1;
        const float freq = exp2f(-(float)(2 * pair) * (13.287712379549449f / 128.0f));
        const float ang = pos * freq;
        const float n = rintf(ang * 0.15915494309189535f);
        const float r = (ang - n * 6.28125f) - n * 1.9353071795864769e-3f;
        float s, c;
        __sincosf(r, &s, &c);
        const float x1 = bf2f(xv[2 * p]), x2 = bf2f(xv[2 * p + 1]);
        ov[2 * p]     = f2bf(x1 * c - x2 * s);
        ov[2 * p + 1] = f2bf(x1 * s + x2 * c);
    }
    *(short8*)&buf[e0] = ov;
}

// ---------------------------------------------------------------------------
// Causal flash attention, KV split 8 ways across 8 waves (512 thr/block).
// Block = (b,h,qt): 16 q-rows; wave w takes KV tiles t == w (mod 8), private
// online-softmax state; 3-phase LDS tree merge at the end (fp32 throughout).
// XCD-pinned: id%8 -> (b,h). LDS 33 KB -> 3 blocks/CU; VGPR ~84 -> 24 waves/CU.
// ---------------------------------------------------------------------------
__global__ __launch_bounds__(512) void flash_kernel(
    const short* __restrict__ qh, const short* __restrict__ kh,
    const short* __restrict__ vT, short* __restrict__ attn)
{
    __shared__ float Osf[4 * 2048];    // tree-merge buffer [wi][col 0..127][row 0..15], 32 KB
    __shared__ float Ms[128], Lp[128]; // per-wave m / rescaled l  (w*16+row)
    short* Ps = (short*)Osf;           // P scratch aliases Osf (dead before merge)

    const int id = blockIdx.x;
    const int hb = id & 7;
    const int b = hb & 1;
    const int h = hb >> 1;
    const int qt = 127 - (id >> 3);    // heavy tiles first
    const int q0 = qt * 16;
    const int tid = threadIdx.x;
    const int w = tid >> 6;
    const int lane = tid & 63;
    const int l15 = lane & 15;
    const int quad = lane >> 4;

    const short* qrow = qh + (size_t)(b * 2048 + q0 + l15) * 512 + h * 128;
    short8 aq[4];
#pragma unroll
    for (int kk = 0; kk < 4; kk++)
        aq[kk] = *(const short8*)&qrow[kk * 32 + quad * 8];

    f32x4 o[8];
#pragma unroll
    for (int dt = 0; dt < 8; dt++) o[dt] = zero4();
    float mrow[4], lrow[4];
#pragma unroll
    for (int r = 0; r < 4; r++) { mrow[r] = -1e30f; lrow[r] = 0.0f; }

    const float scale = 0.08838834764831845f;
    const int ntiles = (q0 + 47) >> 5;   // ceil((q0+16)/32)
    const short* kbp = kh + (size_t)(b * 2048) * 512 + h * 128;
    const short* vbp = vT + (size_t)(h * 128) * 4096 + b * 2048;
    short* pw = &Ps[w * 640];            // per-wave 16x40 P scratch

    for (int t = w; t < ntiles; t += 8) {
        const int kb0 = t * 32;

        // ---- S = Q K^T (16q x 32k) ----
        f32x4 sc[2];
#pragma unroll
        for (int ct = 0; ct < 2; ct++) {
            sc[ct] = zero4();
            const short* kr = kbp + (size_t)(kb0 + ct * 16 + l15) * 512;
#pragma unroll
            for (int kk = 0; kk < 4; kk++) {
                short8 bk = *(const short8*)&kr[kk * 32 + quad * 8];
                sc[ct] = __builtin_amdgcn_mfma_f32_16x16x32_bf16(aq[kk], bk, sc[ct], 0, 0, 0);
            }
        }

        // ---- hoist V frags: latency hides under softmax ----
        short8 bv[8];
#pragma unroll
        for (int dt = 0; dt < 8; dt++)
            bv[dt] = *(const short8*)&vbp[(size_t)(dt * 16 + l15) * 4096 + kb0 + quad * 8];

        // ---- scale + causal mask ----
        const int rbase = q0 + quad * 4;
        float s[2][4];
#pragma unroll
        for (int ct = 0; ct < 2; ct++) {
            const int kcol = kb0 + ct * 16 + l15;
#pragma unroll
            for (int r = 0; r < 4; r++) {
                float vv = sc[ct][r] * scale;
                s[ct][r] = (kcol > rbase + r) ? -1e30f : vv;
            }
        }

        // ---- online softmax (reduce across the 16-lane row group) ----
#pragma unroll
        for (int r = 0; r < 4; r++) {
            float mx = fmaxf(s[0][r], s[1][r]);
#pragma unroll
            for (int off = 1; off < 16; off <<= 1)
                mx = fmaxf(mx, __shfl_xor(mx, off, 64));
            const float mnew = fmaxf(mrow[r], mx);
            const float alpha = __expf(mrow[r] - mnew);
            float p0 = __expf(s[0][r] - mnew);
            float p1 = __expf(s[1][r] - mnew);
            s[0][r] = p0; s[1][r] = p1;
            float psum = p0 + p1;
#pragma unroll
            for (int off = 1; off < 16; off <<= 1)
                psum += __shfl_xor(psum, off, 64);
            lrow[r] = alpha * lrow[r] + psum;
            mrow[r] = mnew;
#pragma unroll
            for (int dt = 0; dt < 8; dt++) o[dt][r] *= alpha;
        }

        // ---- P -> per-wave LDS (A-operand layout); intra-wave, no barrier ----
#pragma unroll
        for (int ct = 0; ct < 2; ct++)
#pragma unroll
            for (int r = 0; r < 4; r++)
                pw[(quad * 4 + r) * 40 + ct * 16 + l15] = f2bf(s[ct][r]);
        short8 ap = *(const short8*)&pw[l15 * 40 + quad * 8];

        // ---- O += P V ----
#pragma unroll
        for (int dt = 0; dt < 8; dt++)
            o[dt] = __builtin_amdgcn_mfma_f32_16x16x32_bf16(ap, bv[dt], o[dt], 0, 0, 0);
    }

    // ======== merge 8 waves' online-softmax states ========
    // publish per-wave row maxima
    if (l15 == 0) {
#pragma unroll
        for (int r = 0; r < 4; r++) Ms[w * 16 + quad * 4 + r] = mrow[r];
    }
    __syncthreads();   // Ms visible; Ps (aliased below) now dead

    // rescale to global max, publish rescaled l
#pragma unroll
    for (int r = 0; r < 4; r++) {
        const int row = quad * 4 + r;
        float gm = Ms[row];
#pragma unroll
        for (int j = 1; j < 8; j++) gm = fmaxf(gm, Ms[j * 16 + row]);
        const float f = __expf(mrow[r] - gm);
        if (l15 == 0) Lp[w * 16 + row] = lrow[r] * f;
#pragma unroll
        for (int dt = 0; dt < 8; dt++) o[dt][r] *= f;
    }
    __syncthreads();   // Ms reads done before Osf (aliased) writes

    // 3-phase tree reduce of O partials (fp32), region reused each phase
#pragma unroll
    for (int step = 4; step >= 1; step >>= 1) {
        if (w >= step && w < 2 * step) {
            float* dst = &Osf[(w - step) * 2048];
#pragma unroll
            for (int dt = 0; dt < 8; dt++)
                *(f32x4*)&dst[(dt * 16 + l15) * 16 + quad * 4] = o[dt];
        }
        __syncthreads();
        if (w < step) {
            const float* srcp = &Osf[w * 2048];
#pragma unroll
            for (int dt = 0; dt < 8; dt++)
                o[dt] += *(const f32x4*)&srcp[(dt * 16 + l15) * 16 + quad * 4];
        }
        __syncthreads();
    }

    // wave 0 holds the full sum -> divide by total l, store bf16
    if (w == 0) {
#pragma unroll
        for (int r = 0; r < 4; r++) {
            const int row = quad * 4 + r;
            float L = Lp[row];
#pragma unroll
            for (int j = 1; j < 8; j++) L += Lp[j * 16 + row];
            const float rL = 1.0f / L;
            short* orow = attn + (size_t)(b * 2048 + q0 + row) * 512 + h * 128;
#pragma unroll
            for (int dt = 0; dt < 8; dt++)
                orow[dt * 16 + l15] = f2bf(o[dt][r] * rL);
        }
    }
}

extern "C" void kernel_launch(void* const* d_in, const int* in_sizes, int n_in,
                              void* d_out, int out_size, void* d_ws, size_t ws_size,
                              hipStream_t stream) {
    const float* q  = (const float*)d_in[0];
    const float* k  = (const float*)d_in[1];
    const float* v  = (const float*)d_in[2];
    const float* Wq = (const float*)d_in[3];
    const float* Wk = (const float*)d_in[4];
    const float* Wv = (const float*)d_in[5];
    const float* Wo = (const float*)d_in[6];
    float* out = (float*)d_out;

    const size_t MB = 1024 * 1024;
    // ws (16 MB total, proven size):
    char* ws = (char*)d_ws;
    short* qh   = (short*)(ws);               // [4096,512] bf16, 4 MB (dead after flash)
    short* kh   = (short*)(ws + 4 * MB);      // 4 MB
    short* vT   = (short*)(ws + 8 * MB);      // [512,4096], 4 MB
    short* Wqb  = (short*)(ws + 12 * MB);     // [512,1536] bf16, 1.5 MB (dead after proj)
    short* Wkb  = (short*)(ws + 13 * MB + 512 * 1024);  // 1.5 MB (dead after proj)
    short* attn = (short*)(ws + 12 * MB);     // [4096,512], 4 MB (flash writes over Wqb/Wkb)
    short* Wob  = (short*)(ws);               // [1536,512] bf16, 1.5 MB (over dead qh)
    // d_out (24 MB) doubles as scratch for bf16 activation copies until outproj:
    short* qb   = (short*)d_out;              // [4096,1536] bf16, 12 MB
    short* kb   = (short*)((char*)d_out + 12 * MB);  // 12 MB

    convertA_kernel<<<dim3(3072, 1, 4), 256, 0, stream>>>(q, k, Wq, Wk, qb, kb, Wqb, Wkb);
    proj_kernel<<<dim3(4, 32, 3), 256, 0, stream>>>(qb, kb, v, Wqb, Wkb, Wv, qh, kh, vT);
    rope_kernel<<<dim3(1024, 1, 2), 256, 0, stream>>>(qh, kh);
    flash_kernel<<<dim3(1024, 1, 1), 512, 0, stream>>>(qh, kh, vT, attn);
    convertB_kernel<<<dim3(384, 1, 1), 256, 0, stream>>>(Wo, Wob);
    outproj_kernel<<<dim3(12, 32, 1), 256, 0, stream>>>(attn, Wob, out);
}